// Round 6
// baseline (548.024 us; speedup 1.0000x reference)
//
#include <hip/hip_runtime.h>
#include <hip/hip_bf16.h>
#include <stdint.h>

// GAT forward, N=8192, IN=256, OUT=128. Inputs fp32 (adj int32), output fp32.
// softmax_j(a1_i + a2_j | adj) == adj_ij*exp(a2_j)/sum_j adj_ij*exp(a2_j)  (a1 cancels)
// -> out = (adj @ (w*h)) / (adj @ w). One big GEMM over adj (268 MB read = floor).
// k_agg: global_load_lds double-buffered adj staging (int32 in LDS, convert at
// fragment read), XOR-swizzled 16B chunks for conflict-free ds_read_b128.

typedef __attribute__((ext_vector_type(8))) short short8;
typedef __attribute__((ext_vector_type(4))) float float4v;

static __device__ __forceinline__ unsigned short f2bf(float f) {
    union { float f; uint32_t i; } v; v.f = f;
    uint32_t r = v.i + 0x7FFFu + ((v.i >> 16) & 1u);
    return (unsigned short)(r >> 16);
}

// ---- WT[n][k] = bf16(W[k][n]) : 128x256 k-major ----
__global__ void k_transpose_w(const float* __restrict__ W, unsigned short* __restrict__ WT) {
    __shared__ unsigned short tile[32][33];
    int tx = threadIdx.x & 31, ty = threadIdx.x >> 5;
    int n0 = blockIdx.x * 32, k0 = blockIdx.y * 32;
    for (int i = 0; i < 4; i++)
        tile[ty + 8 * i][tx] = f2bf(W[(k0 + ty + 8 * i) * 128 + n0 + tx]);
    __syncthreads();
    for (int i = 0; i < 4; i++)
        WT[(size_t)(n0 + ty + 8 * i) * 256 + k0 + tx] = tile[tx][ty + 8 * i];
}

// ---- fused: h = F@W+b (MFMA) -> w = exp(h.a2w+a2b) -> whT rows 0..128 ----
__global__ __launch_bounds__(256) void k_h_fused(const float* __restrict__ F,
                                                 const unsigned short* __restrict__ WT,
                                                 const float* __restrict__ bvec,
                                                 const float* __restrict__ a2w,
                                                 const float* __restrict__ a2b,
                                                 unsigned short* __restrict__ whT) {
    __shared__ __align__(16) unsigned short As[64 * 72];
    __shared__ __align__(16) unsigned short Bs[128 * 72];
    __shared__ __align__(16) unsigned short T[129 * 72];   // [col][row_local]
    __shared__ float bs[128], aw[128], ab_s;

    int t = threadIdx.x, lane = t & 63, wave = t >> 6;
    int rb = blockIdx.x * 64;
    if (t < 128) { bs[t] = bvec[t]; aw[t] = a2w[t]; }
    if (t == 0) ab_s = a2b[0];

    float4v acc[8];
    for (int c = 0; c < 8; c++) acc[c] = (float4v)0.0f;

    for (int kt = 0; kt < 4; kt++) {
        int k0 = kt * 64;
        for (int i = 0; i < 2; i++) {                       // A: 64x64 fp32 -> bf16
            int flat = t + 256 * i, row = flat >> 3, part = flat & 7;
            const float* fp = F + (size_t)(rb + row) * 256 + k0 + part * 8;
            float4 v0 = *reinterpret_cast<const float4*>(fp);
            float4 v1 = *reinterpret_cast<const float4*>(fp + 4);
            uint4 v;
            v.x = f2bf(v0.x) | ((uint32_t)f2bf(v0.y) << 16);
            v.y = f2bf(v0.z) | ((uint32_t)f2bf(v0.w) << 16);
            v.z = f2bf(v1.x) | ((uint32_t)f2bf(v1.y) << 16);
            v.w = f2bf(v1.z) | ((uint32_t)f2bf(v1.w) << 16);
            *reinterpret_cast<uint4*>(&As[row * 72 + part * 8]) = v;
        }
        for (int i = 0; i < 4; i++) {                       // B: 128x64 bf16 k-major
            int flat = t + 256 * i, n = flat >> 3, part = flat & 7;
            *reinterpret_cast<uint4*>(&Bs[n * 72 + part * 8]) =
                *reinterpret_cast<const uint4*>(WT + (size_t)n * 256 + k0 + part * 8);
        }
        __syncthreads();
        int m = lane & 15, kq = lane >> 4;
        for (int ks = 0; ks < 2; ks++) {
            short8 af = *reinterpret_cast<const short8*>(&As[(wave * 16 + m) * 72 + ks * 32 + kq * 8]);
            for (int c = 0; c < 8; c++) {
                short8 bfr = *reinterpret_cast<const short8*>(&Bs[(c * 16 + m) * 72 + ks * 32 + kq * 8]);
                acc[c] = __builtin_amdgcn_mfma_f32_16x16x32_bf16(af, bfr, acc[c], 0, 0, 0);
            }
        }
        __syncthreads();
    }

    // epilogue: bias, per-row a2 dot (reduce over 16-lane m-group), exp, scale
    int m = lane & 15, kq = lane >> 4;
    float hv[8][4], part[4];
    for (int r = 0; r < 4; r++) part[r] = 0.0f;
    for (int c = 0; c < 8; c++) {
        float bb = bs[c * 16 + m], a = aw[c * 16 + m];
        for (int r = 0; r < 4; r++) { hv[c][r] = acc[c][r] + bb; part[r] += hv[c][r] * a; }
    }
    for (int off = 1; off < 16; off <<= 1)
        for (int r = 0; r < 4; r++) part[r] += __shfl_xor(part[r], off, 64);
    float wr[4];
    for (int r = 0; r < 4; r++) {
        float e = fminf(fmaxf(part[r] + ab_s, -60.0f), 60.0f);
        wr[r] = expf(e);
    }
    int rl = wave * 16 + kq * 4;
    for (int c = 0; c < 8; c++)
        for (int r = 0; r < 4; r++)
            T[(c * 16 + m) * 72 + rl + r] = f2bf(hv[c][r] * wr[r]);
    if (m == 0)
        for (int r = 0; r < 4; r++)
            T[128 * 72 + rl + r] = f2bf(wr[r]);
    __syncthreads();

    // store all 129 rows x 64 shorts = 1032 uint4s
    for (int i = 0; i < 5; i++) {
        int flat = t + 256 * i;
        if (flat < 1032) {
            int row = flat >> 3, part = flat & 7;
            *reinterpret_cast<uint4*>(whT + (size_t)row * 8192 + rb + part * 8) =
                *reinterpret_cast<const uint4*>(&T[row * 72 + part * 8]);
        }
    }
}

// ---- KMAIN: C[8192][144] += adj_bf16 @ whT^T. BM=64, BK=64x16, split-K=8. ----
// adj DMA'd to LDS as int32 via global_load_lds (16B/lane), double-buffered.
// LDS layout: 16B chunks, chunk(r, c16) stored at linear r*16 + (c16 ^ (r&15)).
__global__ __launch_bounds__(256) void k_agg(const int* __restrict__ adj,
                                             const unsigned short* __restrict__ whT,
                                             float* __restrict__ C) {
    __shared__ __align__(16) int Abuf[2][64 * 64];          // 2 x 16 KB
    int bx = blockIdx.x;
    int rowtile = bx & 127, ksplit = bx >> 7;
    int rb = rowtile * 64;
    int kbase = ksplit * 1024;
    int t = threadIdx.x, lane = t & 63, wave = t >> 6;
    int m = lane & 15, kq = lane >> 4;

    float4v acc[9];
    for (int c = 0; c < 9; c++) acc[c] = (float4v)0.0f;

    // DMA one 64x64-int tile (16 KB): 4 calls/wave, 1 KB each (64 lanes x 16 B)
    auto dma_tile = [&](int tt, int b) {
        int k0 = kbase + tt * 64;
        #pragma unroll
        for (int i = 0; i < 4; i++) {
            int base_chunk = (wave * 4 + i) * 64;
            int L = base_chunk + lane;
            int r = L >> 4, sc = L & 15;
            int c16 = sc ^ (r & 15);                        // XOR swizzle (within 256B row seg)
            const int* g = adj + (size_t)(rb + r) * 8192 + k0 + c16 * 4;
            __builtin_amdgcn_global_load_lds(
                (const __attribute__((address_space(1))) unsigned int*)g,
                (__attribute__((address_space(3))) unsigned int*)&Abuf[b][base_chunk * 4],
                16, 0, 0);
        }
    };

    dma_tile(0, 0);
    __syncthreads();

    for (int tt = 0; tt < 16; tt++) {
        int cur = tt & 1;
        if (tt < 15) dma_tile(tt + 1, cur ^ 1);
        int r = wave * 16 + m;
        #pragma unroll
        for (int ks = 0; ks < 2; ks++) {
            int c0 = ks * 8 + 2 * kq;                       // first of 2 chunks for this frag
            int4 a0 = *reinterpret_cast<const int4*>(&Abuf[cur][(r * 16 + ((c0    ) ^ m)) * 4]);
            int4 a1 = *reinterpret_cast<const int4*>(&Abuf[cur][(r * 16 + ((c0 + 1) ^ m)) * 4]);
            union { uint32_t u[4]; short8 s; } uu;
            uu.u[0] = (uint32_t)(a0.x | (a0.y << 16)) * 0x3F80u;   // {0,1} -> bf16 0/1 packed
            uu.u[1] = (uint32_t)(a0.z | (a0.w << 16)) * 0x3F80u;
            uu.u[2] = (uint32_t)(a1.x | (a1.y << 16)) * 0x3F80u;
            uu.u[3] = (uint32_t)(a1.z | (a1.w << 16)) * 0x3F80u;
            const unsigned short* bbase = whT + (size_t)m * 8192 + kbase + tt * 64 + ks * 32 + kq * 8;
            #pragma unroll
            for (int c = 0; c < 9; c++) {
                short8 bf = *reinterpret_cast<const short8*>(bbase + (size_t)c * 16 * 8192);
                acc[c] = __builtin_amdgcn_mfma_f32_16x16x32_bf16(uu.s, bf, acc[c], 0, 0, 0);
            }
        }
        __syncthreads();   // drains DMA(tt+1) (vmcnt0) + guards buffer reuse
    }

    for (int c = 0; c < 9; c++)
        for (int rr = 0; rr < 4; rr++)
            atomicAdd(&C[(size_t)(rb + wave * 16 + kq * 4 + rr) * 144 + c * 16 + m], acc[c][rr]);
}

// ---- out[j][c] = fp32: C[j][c] / C[j][128] ----
__global__ void k_epi(const float* __restrict__ C, float* __restrict__ out) {
    int flat = blockIdx.x * 256 + threadIdx.x;   // 8192*32
    int j = flat >> 5, c4 = (flat & 31) * 4;
    float4 v = *reinterpret_cast<const float4*>(C + (size_t)j * 144 + c4);
    float rden = 1.0f / C[(size_t)j * 144 + 128];
    float4 o;
    o.x = v.x * rden; o.y = v.y * rden; o.z = v.z * rden; o.w = v.w * rden;
    *reinterpret_cast<float4*>(out + (size_t)j * 128 + c4) = o;
}

extern "C" void kernel_launch(void* const* d_in, const int* in_sizes, int n_in,
                              void* d_out, int out_size, void* d_ws, size_t ws_size,
                              hipStream_t stream) {
    const float* F   = (const float*)d_in[0];     // [8192][256]
    const int*   adj = (const int*)d_in[1];       // [8192][8192] 0/1
    const float* W   = (const float*)d_in[2];     // [256][128]
    const float* bv  = (const float*)d_in[3];     // [128]
    const float* a2w = (const float*)d_in[6];     // [128]  (a1 cancels; d_in[4],[5] unused)
    const float* a2b = (const float*)d_in[7];     // [1]
    float* out = (float*)d_out;                   // [8192][128]

    char* ws = (char*)d_ws;
    unsigned short* whT = (unsigned short*)(ws);            // 2,359,296 B (144 x 8192 bf16)
    float*          Cws = (float*)(ws + 2359296);           // 4,718,592 B (8192 x 144 fp32)
    unsigned short* WT  = (unsigned short*)(ws + 7077888);  //    65,536 B   (total ~7.14 MB)

    k_transpose_w<<<dim3(4, 8), 256, 0, stream>>>(W, WT);
    k_h_fused<<<128, 256, 0, stream>>>(F, WT, bv, a2w, a2b, whT);
    hipMemsetAsync(Cws, 0, (size_t)8192 * 144 * sizeof(float), stream);
    k_agg<<<1024, 256, 0, stream>>>(adj, whT, Cws);
    k_epi<<<1024, 256, 0, stream>>>(Cws, out);
}

// Round 7
// 459.147 us; speedup vs baseline: 1.1936x; 1.1936x over previous
//
#include <hip/hip_runtime.h>
#include <hip/hip_bf16.h>
#include <stdint.h>

// GAT forward, N=8192, IN=256, OUT=128. Inputs fp32 (adj int32), output fp32.
// softmax_j(a1_i + a2_j | adj) == adj_ij*exp(a2_j)/sum_j adj_ij*exp(a2_j)  (a1 cancels)
// -> out = (adj @ (w*h)) / (adj @ w). One big GEMM over adj (268 MB read = floor).
// k_agg v3: barrier-free, LDS-free. Each wave owns 32 rows x 1/8th of K;
// A loaded global->VGPR (adj rows are wave-private - LDS staging was pure overhead),
// B from L2-resident whT. Compiler free to pipeline with fine-grained vmcnt.

typedef __attribute__((ext_vector_type(8))) short short8;
typedef __attribute__((ext_vector_type(4))) float float4v;

static __device__ __forceinline__ unsigned short f2bf(float f) {
    union { float f; uint32_t i; } v; v.f = f;
    uint32_t r = v.i + 0x7FFFu + ((v.i >> 16) & 1u);
    return (unsigned short)(r >> 16);
}

// pack 8 int32 (0/1) -> 8 packed bf16 {0.0, 1.0}
static __device__ __forceinline__ short8 pack01(int4 a, int4 b) {
    union { uint32_t u[4]; short8 s; } v;
    v.u[0] = (uint32_t)(a.x | (a.y << 16)) * 0x3F80u;
    v.u[1] = (uint32_t)(a.z | (a.w << 16)) * 0x3F80u;
    v.u[2] = (uint32_t)(b.x | (b.y << 16)) * 0x3F80u;
    v.u[3] = (uint32_t)(b.z | (b.w << 16)) * 0x3F80u;
    return v.s;
}

// ---- WT[n][k] = bf16(W[k][n]) : 128x256 k-major ----
__global__ void k_transpose_w(const float* __restrict__ W, unsigned short* __restrict__ WT) {
    __shared__ unsigned short tile[32][33];
    int tx = threadIdx.x & 31, ty = threadIdx.x >> 5;
    int n0 = blockIdx.x * 32, k0 = blockIdx.y * 32;
    for (int i = 0; i < 4; i++)
        tile[ty + 8 * i][tx] = f2bf(W[(k0 + ty + 8 * i) * 128 + n0 + tx]);
    __syncthreads();
    for (int i = 0; i < 4; i++)
        WT[(size_t)(n0 + ty + 8 * i) * 256 + k0 + tx] = tile[tx][ty + 8 * i];
}

// ---- fused: h = F@W+b (MFMA) -> w = exp(h.a2w+a2b) -> whT rows 0..128 ----
__global__ __launch_bounds__(256) void k_h_fused(const float* __restrict__ F,
                                                 const unsigned short* __restrict__ WT,
                                                 const float* __restrict__ bvec,
                                                 const float* __restrict__ a2w,
                                                 const float* __restrict__ a2b,
                                                 unsigned short* __restrict__ whT) {
    __shared__ __align__(16) unsigned short As[64 * 72];
    __shared__ __align__(16) unsigned short Bs[128 * 72];
    __shared__ __align__(16) unsigned short T[129 * 72];   // [col][row_local]
    __shared__ float bs[128], aw[128], ab_s;

    int t = threadIdx.x, lane = t & 63, wave = t >> 6;
    int rb = blockIdx.x * 64;
    if (t < 128) { bs[t] = bvec[t]; aw[t] = a2w[t]; }
    if (t == 0) ab_s = a2b[0];

    float4v acc[8];
    for (int c = 0; c < 8; c++) acc[c] = (float4v)0.0f;

    for (int kt = 0; kt < 4; kt++) {
        int k0 = kt * 64;
        for (int i = 0; i < 2; i++) {                       // A: 64x64 fp32 -> bf16
            int flat = t + 256 * i, row = flat >> 3, part = flat & 7;
            const float* fp = F + (size_t)(rb + row) * 256 + k0 + part * 8;
            float4 v0 = *reinterpret_cast<const float4*>(fp);
            float4 v1 = *reinterpret_cast<const float4*>(fp + 4);
            uint4 v;
            v.x = f2bf(v0.x) | ((uint32_t)f2bf(v0.y) << 16);
            v.y = f2bf(v0.z) | ((uint32_t)f2bf(v0.w) << 16);
            v.z = f2bf(v1.x) | ((uint32_t)f2bf(v1.y) << 16);
            v.w = f2bf(v1.z) | ((uint32_t)f2bf(v1.w) << 16);
            *reinterpret_cast<uint4*>(&As[row * 72 + part * 8]) = v;
        }
        for (int i = 0; i < 4; i++) {                       // B: 128x64 bf16 k-major
            int flat = t + 256 * i, n = flat >> 3, part = flat & 7;
            *reinterpret_cast<uint4*>(&Bs[n * 72 + part * 8]) =
                *reinterpret_cast<const uint4*>(WT + (size_t)n * 256 + k0 + part * 8);
        }
        __syncthreads();
        int m = lane & 15, kq = lane >> 4;
        for (int ks = 0; ks < 2; ks++) {
            short8 af = *reinterpret_cast<const short8*>(&As[(wave * 16 + m) * 72 + ks * 32 + kq * 8]);
            for (int c = 0; c < 8; c++) {
                short8 bfr = *reinterpret_cast<const short8*>(&Bs[(c * 16 + m) * 72 + ks * 32 + kq * 8]);
                acc[c] = __builtin_amdgcn_mfma_f32_16x16x32_bf16(af, bfr, acc[c], 0, 0, 0);
            }
        }
        __syncthreads();
    }

    // epilogue: bias, per-row a2 dot (reduce over 16-lane m-group), exp, scale
    int m = lane & 15, kq = lane >> 4;
    float hv[8][4], part[4];
    for (int r = 0; r < 4; r++) part[r] = 0.0f;
    for (int c = 0; c < 8; c++) {
        float bb = bs[c * 16 + m], a = aw[c * 16 + m];
        for (int r = 0; r < 4; r++) { hv[c][r] = acc[c][r] + bb; part[r] += hv[c][r] * a; }
    }
    for (int off = 1; off < 16; off <<= 1)
        for (int r = 0; r < 4; r++) part[r] += __shfl_xor(part[r], off, 64);
    float wr[4];
    for (int r = 0; r < 4; r++) {
        float e = fminf(fmaxf(part[r] + ab_s, -60.0f), 60.0f);
        wr[r] = expf(e);
    }
    int rl = wave * 16 + kq * 4;
    for (int c = 0; c < 8; c++)
        for (int r = 0; r < 4; r++)
            T[(c * 16 + m) * 72 + rl + r] = f2bf(hv[c][r] * wr[r]);
    if (m == 0)
        for (int r = 0; r < 4; r++)
            T[128 * 72 + rl + r] = f2bf(wr[r]);
    __syncthreads();

    for (int i = 0; i < 5; i++) {                           // 129 rows x 64 shorts
        int flat = t + 256 * i;
        if (flat < 1032) {
            int row = flat >> 3, part = flat & 7;
            *reinterpret_cast<uint4*>(whT + (size_t)row * 8192 + rb + part * 8) =
                *reinterpret_cast<const uint4*>(&T[row * 72 + part * 8]);
        }
    }
}

// ---- KMAIN: C[8192][144] += adj @ whT^T, wave-independent, no LDS/barriers ----
// 2048 waves = 512 blocks x 4. Wave: 32 rows (2 MFMA row-frags), K-chunk 1024.
__global__ __launch_bounds__(256) void k_agg(const int* __restrict__ adj,
                                             const unsigned short* __restrict__ whT,
                                             float* __restrict__ C) {
    int wid = blockIdx.x * 4 + (threadIdx.x >> 6);
    int lane = threadIdx.x & 63;
    int m = lane & 15, kq = lane >> 4;
    int rowset = wid >> 3, ksplit = wid & 7;     // 256 rowsets x 8 ksplits
    int rb = rowset * 32;
    int kbase = ksplit * 1024;

    float4v acc[2][9];
    #pragma unroll
    for (int s = 0; s < 2; s++)
        for (int c = 0; c < 9; c++) acc[s][c] = (float4v)0.0f;

    const int* a0 = adj + (size_t)(rb + m) * 8192 + kbase + kq * 8;
    const int* a1 = a0 + (size_t)16 * 8192;
    const unsigned short* bp = whT + (size_t)m * 8192 + kbase + kq * 8;

    #pragma unroll 4
    for (int kk = 0; kk < 1024; kk += 32) {
        int4 x0 = *reinterpret_cast<const int4*>(a0 + kk);
        int4 x1 = *reinterpret_cast<const int4*>(a0 + kk + 4);
        int4 y0 = *reinterpret_cast<const int4*>(a1 + kk);
        int4 y1 = *reinterpret_cast<const int4*>(a1 + kk + 4);
        short8 af0 = pack01(x0, x1);
        short8 af1 = pack01(y0, y1);
        #pragma unroll
        for (int c = 0; c < 9; c++) {
            short8 bf = *reinterpret_cast<const short8*>(bp + kk + (size_t)c * 16 * 8192);
            acc[0][c] = __builtin_amdgcn_mfma_f32_16x16x32_bf16(af0, bf, acc[0][c], 0, 0, 0);
            acc[1][c] = __builtin_amdgcn_mfma_f32_16x16x32_bf16(af1, bf, acc[1][c], 0, 0, 0);
        }
    }

    #pragma unroll
    for (int s = 0; s < 2; s++)
        for (int c = 0; c < 9; c++)
            for (int rr = 0; rr < 4; rr++)
                atomicAdd(&C[(size_t)(rb + s * 16 + kq * 4 + rr) * 144 + c * 16 + m],
                          acc[s][c][rr]);
}

// ---- out[j][c] = fp32: C[j][c] / C[j][128] ----
__global__ void k_epi(const float* __restrict__ C, float* __restrict__ out) {
    int flat = blockIdx.x * 256 + threadIdx.x;   // 8192*32
    int j = flat >> 5, c4 = (flat & 31) * 4;
    float4 v = *reinterpret_cast<const float4*>(C + (size_t)j * 144 + c4);
    float rden = 1.0f / C[(size_t)j * 144 + 128];
    float4 o;
    o.x = v.x * rden; o.y = v.y * rden; o.z = v.z * rden; o.w = v.w * rden;
    *reinterpret_cast<float4*>(out + (size_t)j * 128 + c4) = o;
}

extern "C" void kernel_launch(void* const* d_in, const int* in_sizes, int n_in,
                              void* d_out, int out_size, void* d_ws, size_t ws_size,
                              hipStream_t stream) {
    const float* F   = (const float*)d_in[0];     // [8192][256]
    const int*   adj = (const int*)d_in[1];       // [8192][8192] 0/1
    const float* W   = (const float*)d_in[2];     // [256][128]
    const float* bv  = (const float*)d_in[3];     // [128]
    const float* a2w = (const float*)d_in[6];     // [128]  (a1 cancels; d_in[4],[5] unused)
    const float* a2b = (const float*)d_in[7];     // [1]
    float* out = (float*)d_out;                   // [8192][128]

    char* ws = (char*)d_ws;
    unsigned short* whT = (unsigned short*)(ws);            // 2,359,296 B (144 x 8192 bf16)
    float*          Cws = (float*)(ws + 2359296);           // 4,718,592 B (8192 x 144 fp32)
    unsigned short* WT  = (unsigned short*)(ws + 7077888);  //    65,536 B   (total ~7.14 MB)

    k_transpose_w<<<dim3(4, 8), 256, 0, stream>>>(W, WT);
    k_h_fused<<<128, 256, 0, stream>>>(F, WT, bv, a2w, a2b, whT);
    hipMemsetAsync(Cws, 0, (size_t)8192 * 144 * sizeof(float), stream);
    k_agg<<<512, 256, 0, stream>>>(adj, whT, Cws);
    k_epi<<<1024, 256, 0, stream>>>(Cws, out);
}